// Round 1
// baseline (97.797 us; speedup 1.0000x reference)
//
#include <hip/hip_runtime.h>

// KL(p||q) for diagonal Gaussians, reduced to a scalar:
//   out = (1/(B*L)) * sum_over_all [ log(sq) - log(sp) + 0.5*(sp^2+(mp-mq)^2)/sq^2 - 0.5 ]
// B=16, L=64, N=512, D=64 -> 33,554,432 elements per tensor, 4 fp32 tensors.
// Memory-bound streaming reduction: float4 loads, two-stage deterministic reduce.

#define RED_BLOCKS 2048
#define RED_THREADS 256

__device__ __forceinline__ float wave_reduce_sum(float v) {
    // full 64-lane butterfly
    #pragma unroll
    for (int off = 32; off > 0; off >>= 1)
        v += __shfl_down(v, off, 64);
    return v;
}

__global__ __launch_bounds__(RED_THREADS) void kl_partial_kernel(
        const float4* __restrict__ pmu,
        const float4* __restrict__ psig,
        const float4* __restrict__ qmu,
        const float4* __restrict__ qsig,
        float* __restrict__ partial,
        long n4) {
    long idx    = (long)blockIdx.x * blockDim.x + threadIdx.x;
    long stride = (long)gridDim.x * blockDim.x;

    float acc = 0.0f;
    for (long i = idx; i < n4; i += stride) {
        float4 mp = pmu[i];
        float4 sp = psig[i];
        float4 mq = qmu[i];
        float4 sq = qsig[i];

        {
            float d = mp.x - mq.x;
            float sp2 = sp.x * sp.x;
            float sq2 = sq.x * sq.x;
            acc += __logf(sq.x) - __logf(sp.x) + 0.5f * (sp2 + d * d) / sq2 - 0.5f;
        }
        {
            float d = mp.y - mq.y;
            float sp2 = sp.y * sp.y;
            float sq2 = sq.y * sq.y;
            acc += __logf(sq.y) - __logf(sp.y) + 0.5f * (sp2 + d * d) / sq2 - 0.5f;
        }
        {
            float d = mp.z - mq.z;
            float sp2 = sp.z * sp.z;
            float sq2 = sq.z * sq.z;
            acc += __logf(sq.z) - __logf(sp.z) + 0.5f * (sp2 + d * d) / sq2 - 0.5f;
        }
        {
            float d = mp.w - mq.w;
            float sp2 = sp.w * sp.w;
            float sq2 = sq.w * sq.w;
            acc += __logf(sq.w) - __logf(sp.w) + 0.5f * (sp2 + d * d) / sq2 - 0.5f;
        }
    }

    // wave reduce then block reduce via LDS
    acc = wave_reduce_sum(acc);
    __shared__ float smem[RED_THREADS / 64];
    int lane = threadIdx.x & 63;
    int wid  = threadIdx.x >> 6;
    if (lane == 0) smem[wid] = acc;
    __syncthreads();
    if (threadIdx.x == 0) {
        float s = 0.0f;
        #pragma unroll
        for (int w = 0; w < RED_THREADS / 64; ++w) s += smem[w];
        partial[blockIdx.x] = s;
    }
}

__global__ __launch_bounds__(RED_THREADS) void kl_final_kernel(
        const float* __restrict__ partial,
        float* __restrict__ out,
        int n, float scale) {
    float acc = 0.0f;
    for (int i = threadIdx.x; i < n; i += blockDim.x) acc += partial[i];
    acc = wave_reduce_sum(acc);
    __shared__ float smem[RED_THREADS / 64];
    int lane = threadIdx.x & 63;
    int wid  = threadIdx.x >> 6;
    if (lane == 0) smem[wid] = acc;
    __syncthreads();
    if (threadIdx.x == 0) {
        float s = 0.0f;
        #pragma unroll
        for (int w = 0; w < RED_THREADS / 64; ++w) s += smem[w];
        out[0] = s * scale;
    }
}

extern "C" void kernel_launch(void* const* d_in, const int* in_sizes, int n_in,
                              void* d_out, int out_size, void* d_ws, size_t ws_size,
                              hipStream_t stream) {
    // setup_inputs order: prior_mu, prior_sigma, post_mu, post_sigma (all fp32)
    const float4* pmu  = (const float4*)d_in[0];
    const float4* psig = (const float4*)d_in[1];
    const float4* qmu  = (const float4*)d_in[2];
    const float4* qsig = (const float4*)d_in[3];

    long n  = (long)in_sizes[0];        // 33,554,432
    long n4 = n / 4;                    // float4 count (n is a multiple of 4)

    float* partial = (float*)d_ws;      // RED_BLOCKS floats of scratch
    float* out     = (float*)d_out;

    const float scale = 1.0f / 1024.0f; // 1/(B*L), B=16 L=64

    kl_partial_kernel<<<RED_BLOCKS, RED_THREADS, 0, stream>>>(
        pmu, psig, qmu, qsig, partial, n4);
    kl_final_kernel<<<1, RED_THREADS, 0, stream>>>(
        partial, out, RED_BLOCKS, scale);
}

// Round 3
// 85.863 us; speedup vs baseline: 1.1390x; 1.1390x over previous
//
#include <hip/hip_runtime.h>

// KL(p||q) diagonal Gaussians -> scalar:
//   out = (1/(B*L)) * sum [ 0.5*( (sp^2+(mp-mq)^2)/sq^2 - log(sp^2/sq^2) - 1 ) ]
// 4 fp32 tensors x 33,554,432 elems = 512 MiB read. Latency-bound streaming
// reduction. This round: ext_vector float4 (nontemporal-builtin-compatible),
// register prefetch (double-buffer), single-log math, nt loads on mu streams.

#define RED_BLOCKS 2048
#define RED_THREADS 256

typedef float f32x4 __attribute__((ext_vector_type(4)));

__device__ __forceinline__ float wave_reduce_sum(float v) {
    #pragma unroll
    for (int off = 32; off > 0; off >>= 1)
        v += __shfl_down(v, off, 64);
    return v;
}

// per-float4 KL contribution (single log + single rcp per element)
__device__ __forceinline__ float kl4(f32x4 mp, f32x4 sp, f32x4 mq, f32x4 sq) {
    float acc = 0.0f;
    #pragma unroll
    for (int k = 0; k < 4; ++k) {
        float sp2 = sp[k] * sp[k];
        float sq2 = sq[k] * sq[k];
        float d   = mp[k] - mq[k];
        float inv = __frcp_rn(sq2);
        acc += (sp2 + d * d) * inv - __logf(sp2 * inv) - 1.0f;
    }
    return 0.5f * acc;
}

__global__ __launch_bounds__(RED_THREADS) void kl_partial_kernel(
        const f32x4* __restrict__ pmu,
        const f32x4* __restrict__ psig,
        const f32x4* __restrict__ qmu,
        const f32x4* __restrict__ qsig,
        float* __restrict__ partial,
        long n4) {
    long idx    = (long)blockIdx.x * blockDim.x + threadIdx.x;
    long stride = (long)gridDim.x * blockDim.x;

    float acc = 0.0f;

    long full_iters = n4 / stride;           // 16 at the reference shape
    if (full_iters > 0) {
        long i = idx;
        // mu streams: non-temporal (no L3 pollution); sigma streams: cached.
        f32x4 a = __builtin_nontemporal_load(&pmu[i]);
        f32x4 b = psig[i];
        f32x4 c = __builtin_nontemporal_load(&qmu[i]);
        f32x4 d = qsig[i];
        for (long it = 0; it < full_iters - 1; ++it) {
            long j = i + stride;
            f32x4 a1 = __builtin_nontemporal_load(&pmu[j]);
            f32x4 b1 = psig[j];
            f32x4 c1 = __builtin_nontemporal_load(&qmu[j]);
            f32x4 d1 = qsig[j];
            acc += kl4(a, b, c, d);
            a = a1; b = b1; c = c1; d = d1;
            i = j;
        }
        acc += kl4(a, b, c, d);
    }
    // remainder (empty at the reference shape, kept for generality)
    for (long i = full_iters * stride + idx; i < n4; i += stride) {
        acc += kl4(pmu[i], psig[i], qmu[i], qsig[i]);
    }

    acc = wave_reduce_sum(acc);
    __shared__ float smem[RED_THREADS / 64];
    int lane = threadIdx.x & 63;
    int wid  = threadIdx.x >> 6;
    if (lane == 0) smem[wid] = acc;
    __syncthreads();
    if (threadIdx.x == 0) {
        float s = 0.0f;
        #pragma unroll
        for (int w = 0; w < RED_THREADS / 64; ++w) s += smem[w];
        partial[blockIdx.x] = s;
    }
}

__global__ __launch_bounds__(RED_THREADS) void kl_final_kernel(
        const float* __restrict__ partial,
        float* __restrict__ out,
        int n, float scale) {
    float acc = 0.0f;
    for (int i = threadIdx.x; i < n; i += blockDim.x) acc += partial[i];
    acc = wave_reduce_sum(acc);
    __shared__ float smem[RED_THREADS / 64];
    int lane = threadIdx.x & 63;
    int wid  = threadIdx.x >> 6;
    if (lane == 0) smem[wid] = acc;
    __syncthreads();
    if (threadIdx.x == 0) {
        float s = 0.0f;
        #pragma unroll
        for (int w = 0; w < RED_THREADS / 64; ++w) s += smem[w];
        out[0] = s * scale;
    }
}

extern "C" void kernel_launch(void* const* d_in, const int* in_sizes, int n_in,
                              void* d_out, int out_size, void* d_ws, size_t ws_size,
                              hipStream_t stream) {
    const f32x4* pmu  = (const f32x4*)d_in[0];
    const f32x4* psig = (const f32x4*)d_in[1];
    const f32x4* qmu  = (const f32x4*)d_in[2];
    const f32x4* qsig = (const f32x4*)d_in[3];

    long n  = (long)in_sizes[0];
    long n4 = n / 4;

    float* partial = (float*)d_ws;
    float* out     = (float*)d_out;

    const float scale = 1.0f / 1024.0f;  // 1/(B*L)

    kl_partial_kernel<<<RED_BLOCKS, RED_THREADS, 0, stream>>>(
        pmu, psig, qmu, qsig, partial, n4);
    kl_final_kernel<<<1, RED_THREADS, 0, stream>>>(
        partial, out, RED_BLOCKS, scale);
}